// Round 22
// baseline (348.263 us; speedup 1.0000x reference)
//
#include <hip/hip_runtime.h>
#include <hip/hip_bf16.h>
#include <hip/hip_fp8.h>
#include <stdint.h>

#define NN 100000
#define NE 600000
#define ND 128
#define ED 32
#define HID 128
#define SCANB 391        // ceil(NN/256)
#define NEB 4688         // ceil(NE/128) edge blocks (tail: 64 rows)

using short8 = __attribute__((ext_vector_type(8))) short;
using f32x4  = __attribute__((ext_vector_type(4))) float;
using f32x2  = __attribute__((ext_vector_type(2))) float;

// ---------- bf16 helpers (manual RNE, deterministic) ----------
__device__ __forceinline__ uint32_t f2bf(float f) {
  uint32_t u = __float_as_uint(f);
  return (u + 0x7FFFu + ((u >> 16) & 1u)) >> 16;
}
__device__ __forceinline__ float bf2f(uint32_t h) {
  return __uint_as_float(h << 16);
}
__device__ __forceinline__ short8 pack8(float4 a, float4 b) {
  short8 s;
  s[0] = (short)f2bf(a.x); s[1] = (short)f2bf(a.y);
  s[2] = (short)f2bf(a.z); s[3] = (short)f2bf(a.w);
  s[4] = (short)f2bf(b.x); s[5] = (short)f2bf(b.y);
  s[6] = (short)f2bf(b.z); s[7] = (short)f2bf(b.w);
  return s;
}

// ---------- fp8 e4m3 helpers (HW cvt on gfx950; header fallback) ----------
__device__ __forceinline__ uint8_t fp8_enc(float v) {
#if __has_builtin(__builtin_amdgcn_cvt_pk_fp8_f32)
  return (uint8_t)(__builtin_amdgcn_cvt_pk_fp8_f32(v, v, 0, false) & 0xFF);
#else
  __hip_fp8_e4m3 q(v);
  return q.__x;
#endif
}
__device__ __forceinline__ float2 fp8_dec2(uint32_t v) {
#if __has_builtin(__builtin_amdgcn_cvt_pk_f32_fp8)
  f32x2 r = __builtin_amdgcn_cvt_pk_f32_fp8((int)v, false);
  return make_float2(r[0], r[1]);
#else
  __hip_fp8_e4m3 qa, qb;
  qa.__x = (uint8_t)(v & 0xFF); qb.__x = (uint8_t)((v >> 8) & 0xFF);
  return make_float2((float)qa, (float)qb);
#endif
}
// pack two float4 into 8 fp8 bytes, returned as the MFMA A-operand long
__device__ __forceinline__ long pack_fp8x8(float4 a, float4 b) {
  union { uint8_t u8[8]; long l; } u;
  u.u8[0] = fp8_enc(a.x); u.u8[1] = fp8_enc(a.y);
  u.u8[2] = fp8_enc(a.z); u.u8[3] = fp8_enc(a.w);
  u.u8[4] = fp8_enc(b.x); u.u8[5] = fp8_enc(b.y);
  u.u8[6] = fp8_enc(b.z); u.u8[7] = fp8_enc(b.w);
  return u.l;
}

// ---------- combined weight pre-pack + cnt/counter zeroing, one launch ----------
__global__ __launch_bounds__(256) void k_prep_all(
    const float* __restrict__ uW1, const float* __restrict__ uW2,
    const float* __restrict__ W1, const float* __restrict__ W2,
    short* __restrict__ U1p, short* __restrict__ U2p,
    uint8_t* __restrict__ W1p8, uint8_t* __restrict__ W2p8,
    int* __restrict__ cnt, int* __restrict__ counter) {
  int o = blockIdx.x * 256 + threadIdx.x;
  if (o < NN) cnt[o] = 0;
  if (o == 0) *counter = 0;
  const float* src; int rel; int isFp8;
  short* dstS = nullptr; uint8_t* dst8 = nullptr;
  if (o < 32768)       { rel = o;         src = uW1; dstS = U1p;  isFp8 = 0; }
  else if (o < 49152)  { rel = o - 32768; src = uW2; dstS = U2p;  isFp8 = 0; }
  else if (o < 86016)  { rel = o - 49152; src = W1;  dst8 = W1p8; isFp8 = 1; }
  else if (o < 102400) { rel = o - 86016; src = W2;  dst8 = W2p8; isFp8 = 1; }
  else return;
  int j = rel & 7, c16 = (rel >> 3) & 15, g = (rel >> 7) & 3, nt = (rel >> 9) & 7, c = rel >> 12;
  int k = c * 32 + g * 8 + j, n = nt * 16 + c16;
  float v = src[k * 128 + n];
  if (isFp8) dst8[rel] = fp8_enc(v);
  else       dstS[rel] = (short)f2bf(v);
}

// ---------- node features fp32 -> bf16 + fp8; fused histogram ----------
__global__ __launch_bounds__(256) void k_prep_nf(const float* __restrict__ nf,
                                                 short* __restrict__ nfb,
                                                 uint8_t* __restrict__ nfb8,
                                                 const int* __restrict__ ei,
                                                 int* __restrict__ cnt) {
  const int total = NN * ND / 8;
  int gid = blockIdx.x * 256 + threadIdx.x;
  for (int e = gid; e < NE; e += gridDim.x * 256)
    atomicAdd(&cnt[ei[NE + e]], 1);
  for (int u = gid; u < total; u += gridDim.x * 256) {
    const float* s = nf + (size_t)u * 8;
    float4 v0 = *(const float4*)s, v1 = *(const float4*)(s + 4);
    *(short8*)(nfb + (size_t)u * 8) = pack8(v0, v1);
    uint8_t b[8];
    b[0] = fp8_enc(v0.x); b[1] = fp8_enc(v0.y); b[2] = fp8_enc(v0.z); b[3] = fp8_enc(v0.w);
    b[4] = fp8_enc(v1.x); b[5] = fp8_enc(v1.y); b[6] = fp8_enc(v1.z); b[7] = fp8_enc(v1.w);
    *(uint2*)(nfb8 + (size_t)u * 8) = *(const uint2*)b;
  }
}

// ---------- edge MLP: full fp8, 128-row tile, 4 blocks/CU (R21, unchanged) ----------
__global__ __launch_bounds__(256, 4) void k_edge_mfma(
    const uint8_t* __restrict__ nfb8, const float* __restrict__ ef,
    const uint8_t* __restrict__ W1p8, const float* __restrict__ b1,
    const uint8_t* __restrict__ W2p8, const float* __restrict__ b2,
    const float* __restrict__ aW, const int* __restrict__ ei,
    const int* __restrict__ perm,
    uint8_t* __restrict__ msg8, float* __restrict__ logits) {
  __shared__ __align__(16) uint8_t sRow[128 * 136];
  __shared__ __align__(16) uint8_t sCol[128 * 136];
  __shared__ __align__(16) uint8_t sB8[4096];
  __shared__ int sIdx[256];
  __shared__ int sPerm[128];

  const int tid = threadIdx.x;
  const int wv = tid >> 6, ln = tid & 63, cr = ln & 15, gp = ln >> 4;
  const int e0 = blockIdx.x * 128;
  const int wrow = wv * 32;

  if (tid < 128) {
    int e = e0 + tid; if (e >= NE) e = NE - 1;
    sIdx[tid] = ei[e];
    sIdx[128 + tid] = ei[NE + e];
    sPerm[tid] = perm[e];
  }
  __syncthreads();

  // single gather pass: both endpoint rows, full 128B lines
#pragma unroll
  for (int it = 0; it < 16; ++it) {
    int t = it * 256 + tid;
    int side = t >> 11;
    int r = (t & 2047) >> 4;
    int o = (t & 15) * 8;
    const uint8_t* src = nfb8 + (size_t)sIdx[side * 128 + r] * ND + o;
    uint8_t* dst = (side ? sCol : sRow) + r * 136 + o;
    *(uint2*)dst = *(const uint2*)src;
  }

  // ef chunk (c==8) operands: direct global reads, packed in-register
  long efA0, efA1;
  {
    int ea = e0 + wrow + cr;      if (ea >= NE) ea = NE - 1;
    int eb = e0 + wrow + 16 + cr; if (eb >= NE) eb = NE - 1;
    const float* f0 = ef + (size_t)ea * ED + gp * 8;
    const float* f1 = ef + (size_t)eb * ED + gp * 8;
    efA0 = pack_fp8x8(*(const float4*)f0, *(const float4*)(f0 + 4));
    efA1 = pack_fp8x8(*(const float4*)f1, *(const float4*)(f1 + 4));
  }

  float bia[8], aWr[8], bia2[8];
#pragma unroll
  for (int nt = 0; nt < 8; ++nt) {
    bia[nt] = b1[nt * 16 + cr];
    bia2[nt] = b2[nt * 16 + cr];
    aWr[nt] = aW[nt * 16 + cr];
  }
  f32x4 acc[2][8];
#pragma unroll
  for (int mt = 0; mt < 2; ++mt)
#pragma unroll
    for (int nt = 0; nt < 8; ++nt)
      acc[mt][nt] = (f32x4){bia[nt], bia[nt], bia[nt], bia[nt]};

  // layer 1: 9 fp8 chunks, single-buffered sB (2 barriers/chunk)
  for (int c = 0; c < 9; ++c) {
    __syncthreads();
    *(uint4*)&sB8[tid * 16] = *(const uint4*)(W1p8 + c * 4096 + tid * 16);
    __syncthreads();
    long af0, af1;
    if (c < 8) {
      const uint8_t* aSrc = (c < 4) ? (sRow + c * 32) : (sCol + (c - 4) * 32);
      af0 = *(const long*)(aSrc + (wrow + cr) * 136 + gp * 8);
      af1 = *(const long*)(aSrc + (wrow + 16 + cr) * 136 + gp * 8);
    } else {
      af0 = efA0; af1 = efA1;
    }
#pragma unroll
    for (int nt = 0; nt < 8; ++nt) {
      long bfr = *(const long*)&sB8[(nt * 4 + gp) * 128 + cr * 8];
      acc[0][nt] = __builtin_amdgcn_mfma_f32_16x16x32_fp8_fp8(af0, bfr, acc[0][nt], 0, 0, 0);
      acc[1][nt] = __builtin_amdgcn_mfma_f32_16x16x32_fp8_fp8(af1, bfr, acc[1][nt], 0, 0, 0);
    }
  }

  // relu(h) -> fp8 into sRow (wave-private rows)
#pragma unroll
  for (int mt = 0; mt < 2; ++mt)
#pragma unroll
    for (int nt = 0; nt < 8; ++nt)
#pragma unroll
      for (int rr = 0; rr < 4; ++rr)
        sRow[(wrow + mt * 16 + gp * 4 + rr) * 136 + nt * 16 + cr] =
            fp8_enc(fmaxf(acc[mt][nt][rr], 0.f));

  // layer 2: 4 fp8 chunks, single-buffered sB
  f32x4 acc2[2][8];
#pragma unroll
  for (int mt = 0; mt < 2; ++mt)
#pragma unroll
    for (int nt = 0; nt < 8; ++nt)
      acc2[mt][nt] = (f32x4){bia2[nt], bia2[nt], bia2[nt], bia2[nt]};
  for (int c2 = 0; c2 < 4; ++c2) {
    __syncthreads();
    *(uint4*)&sB8[tid * 16] = *(const uint4*)(W2p8 + c2 * 4096 + tid * 16);
    __syncthreads();
    long af0 = *(const long*)&sRow[(wrow + cr) * 136 + c2 * 32 + gp * 8];
    long af1 = *(const long*)&sRow[(wrow + 16 + cr) * 136 + c2 * 32 + gp * 8];
#pragma unroll
    for (int nt = 0; nt < 8; ++nt) {
      long bfr = *(const long*)&sB8[(nt * 4 + gp) * 128 + cr * 8];
      acc2[0][nt] = __builtin_amdgcn_mfma_f32_16x16x32_fp8_fp8(af0, bfr, acc2[0][nt], 0, 0, 0);
      acc2[1][nt] = __builtin_amdgcn_mfma_f32_16x16x32_fp8_fp8(af1, bfr, acc2[1][nt], 0, 0, 0);
    }
  }

  // attention logits -> CSR slot (guarded for tail)
#pragma unroll
  for (int mt = 0; mt < 2; ++mt)
#pragma unroll
    for (int rr = 0; rr < 4; ++rr) {
      float p = 0.f;
#pragma unroll
      for (int nt = 0; nt < 8; ++nt) p += acc2[mt][nt][rr] * aWr[nt];
      p += __shfl_xor(p, 1, 64);
      p += __shfl_xor(p, 2, 64);
      p += __shfl_xor(p, 4, 64);
      p += __shfl_xor(p, 8, 64);
      int row = wrow + mt * 16 + gp * 4 + rr;
      if (cr == 0 && e0 + row < NE) logits[sPerm[row]] = p;
    }

  // messages -> sCol (fp8) -> 128B rows scattered to CSR slots (guarded)
#pragma unroll
  for (int mt = 0; mt < 2; ++mt)
#pragma unroll
    for (int nt = 0; nt < 8; ++nt)
#pragma unroll
      for (int rr = 0; rr < 4; ++rr)
        sCol[(wrow + mt * 16 + gp * 4 + rr) * 136 + nt * 16 + cr] =
            fp8_enc(acc2[mt][nt][rr]);
  __syncthreads();
#pragma unroll
  for (int it = 0; it < 8; ++it) {
    int row = it * 16 + (tid >> 4), o8 = (tid & 15) * 8;
    if (e0 + row < NE)
      *(uint2*)(msg8 + (size_t)sPerm[row] * HID + o8) = *(const uint2*)&sCol[row * 136 + o8];
  }
}

// ---------- FUSED node kernel: per-wave CSR aggregation + 2-layer MLP ----------
// Wave w owns rows [wrow, wrow+32): aggregates its nodes' msg rows into sBuf
// (bf16), then layer-1 reads chunks 4-7 from sBuf; h overwrites sBuf; layer-2;
// residual. All sBuf rows wave-private -> ZERO barriers. LDS 34.8KB -> 4 blk/CU.
__global__ __launch_bounds__(256, 4) void k_node_fused(
    const short* __restrict__ nfb, const uint8_t* __restrict__ msg8,
    const float* __restrict__ logits, const int* __restrict__ rowptr,
    const float* __restrict__ red,
    const short* __restrict__ U1p, const float* __restrict__ b1,
    const short* __restrict__ U2p, const float* __restrict__ b2,
    float* __restrict__ out) {
  __shared__ __align__(16) short sBuf[128 * 136];

  const int tid = threadIdx.x;
  const int wv = tid >> 6, ln = tid & 63, cr = ln & 15, gp = ln >> 4;
  const int n0 = blockIdx.x * 128;
  const int wrow = wv * 32;
  const float gm = red[0], inv = red[1];

  // ---- phase 1: aggregate this wave's 32 node rows into sBuf (bf16) ----
  for (int j = 0; j < 32; ++j) {
    int n = n0 + wrow + j;
    if (n >= NN) break;            // uniform across the wave
    int i0 = rowptr[n], i1 = rowptr[n + 1];
    float a0 = 0.f, a1 = 0.f;
    for (int i = i0; i < i1; ++i) {
      float wt = expf(logits[i] - gm) * inv;
      uint32_t pk = *(const uint16_t*)(msg8 + (size_t)i * HID + ln * 2);
      float2 d = fp8_dec2(pk);
      a0 += wt * d.x;
      a1 += wt * d.y;
    }
    uint32_t packed = f2bf(a0) | (f2bf(a1) << 16);
    *(uint32_t*)&sBuf[(wrow + j) * 136 + ln * 2] = packed;
  }
  // no barrier: all sBuf rows this wave reads below are its own

  int na0 = n0 + wrow + cr;      if (na0 >= NN) na0 = NN - 1;
  int na1 = n0 + wrow + 16 + cr; if (na1 >= NN) na1 = NN - 1;

  float bia[8], bia2[8];
#pragma unroll
  for (int nt = 0; nt < 8; ++nt) {
    bia[nt] = b1[nt * 16 + cr];
    bia2[nt] = b2[nt * 16 + cr];
  }
  f32x4 acc[2][8];
#pragma unroll
  for (int mt = 0; mt < 2; ++mt)
#pragma unroll
    for (int nt = 0; nt < 8; ++nt)
      acc[mt][nt] = (f32x4){bia[nt], bia[nt], bia[nt], bia[nt]};

  // ---- layer 1: K = 256 (chunks 0-3: nfb direct, 4-7: sBuf agg) ----
#pragma unroll
  for (int c = 0; c < 8; ++c) {
    short8 af0, af1;
    if (c < 4) {
      const int ko = c * 32 + gp * 8;
      af0 = *(const short8*)(nfb + (size_t)na0 * ND + ko);
      af1 = *(const short8*)(nfb + (size_t)na1 * ND + ko);
    } else {
      const int ko = (c - 4) * 32 + gp * 8;
      af0 = *(const short8*)&sBuf[(wrow + cr) * 136 + ko];
      af1 = *(const short8*)&sBuf[(wrow + 16 + cr) * 136 + ko];
    }
    const short* Wc = U1p + c * 4096;
#pragma unroll
    for (int nt = 0; nt < 8; ++nt) {
      short8 bfr = *(const short8*)(Wc + (nt * 4 + gp) * 128 + cr * 8);
      acc[0][nt] = __builtin_amdgcn_mfma_f32_16x16x32_bf16(af0, bfr, acc[0][nt], 0, 0, 0);
      acc[1][nt] = __builtin_amdgcn_mfma_f32_16x16x32_bf16(af1, bfr, acc[1][nt], 0, 0, 0);
    }
  }

  // relu -> sBuf overwrite (wave-private rows; all layer-1 sBuf reads done)
#pragma unroll
  for (int mt = 0; mt < 2; ++mt)
#pragma unroll
    for (int nt = 0; nt < 8; ++nt)
#pragma unroll
      for (int rr = 0; rr < 4; ++rr)
        sBuf[(wrow + mt * 16 + gp * 4 + rr) * 136 + nt * 16 + cr] =
            (short)f2bf(fmaxf(acc[mt][nt][rr], 0.f));

  // ---- layer 2: K = 128 from sBuf ----
  f32x4 acc2[2][8];
#pragma unroll
  for (int mt = 0; mt < 2; ++mt)
#pragma unroll
    for (int nt = 0; nt < 8; ++nt)
      acc2[mt][nt] = (f32x4){bia2[nt], bia2[nt], bia2[nt], bia2[nt]};
#pragma unroll
  for (int c2 = 0; c2 < 4; ++c2) {
    short8 af0 = *(const short8*)&sBuf[(wrow + cr) * 136 + c2 * 32 + gp * 8];
    short8 af1 = *(const short8*)&sBuf[(wrow + 16 + cr) * 136 + c2 * 32 + gp * 8];
    const short* Wc = U2p + c2 * 4096;
#pragma unroll
    for (int nt = 0; nt < 8; ++nt) {
      short8 bfr = *(const short8*)(Wc + (nt * 4 + gp) * 128 + cr * 8);
      acc2[0][nt] = __builtin_amdgcn_mfma_f32_16x16x32_bf16(af0, bfr, acc2[0][nt], 0, 0, 0);
      acc2[1][nt] = __builtin_amdgcn_mfma_f32_16x16x32_bf16(af1, bfr, acc2[1][nt], 0, 0, 0);
    }
  }

  // residual (bf16 nfb) + store
#pragma unroll
  for (int mt = 0; mt < 2; ++mt)
#pragma unroll
    for (int rr = 0; rr < 4; ++rr) {
      int n = n0 + wrow + mt * 16 + gp * 4 + rr;
      if (n < NN) {
#pragma unroll
        for (int nt = 0; nt < 8; ++nt) {
          int col = nt * 16 + cr;
          float r = bf2f((uint16_t)nfb[(size_t)n * ND + col]);
          out[(size_t)n * ND + col] = acc2[mt][nt][rr] + r;
        }
      }
    }
}

// ---------- fused online softmax reduction: partials + last-block final ----------
__device__ __forceinline__ void ms_combine(float& m, float& s, float m2, float s2) {
  float M = fmaxf(m, m2);
  s = s * expf(m - M) + s2 * expf(m2 - M);
  m = M;
}
__device__ __forceinline__ void ms_block_reduce(float& m, float& s) {
#pragma unroll
  for (int o = 1; o < 64; o <<= 1) {
    float m2 = __shfl_xor(m, o, 64), s2 = __shfl_xor(s, o, 64);
    ms_combine(m, s, m2, s2);
  }
  __shared__ float sm[4], ss[4];
  if ((threadIdx.x & 63) == 0) { sm[threadIdx.x >> 6] = m; ss[threadIdx.x >> 6] = s; }
  __syncthreads();
  m = sm[0]; s = ss[0];
  ms_combine(m, s, sm[1], ss[1]);
  ms_combine(m, s, sm[2], ss[2]);
  ms_combine(m, s, sm[3], ss[3]);
}
__global__ __launch_bounds__(256) void k_red(const float* __restrict__ logits,
                                             float* __restrict__ pmax,
                                             float* __restrict__ psum,
                                             float* __restrict__ red,
                                             int* __restrict__ counter) {
  float m = -3.402823466e38f, s = 0.f;
  for (int i = blockIdx.x * 256 + threadIdx.x; i < NE; i += 1024 * 256) {
    float l = logits[i];
    if (l <= m) s += expf(l - m);
    else { s = s * expf(m - l) + 1.f; m = l; }
  }
  ms_block_reduce(m, s);
  __shared__ int lastFlag;
  if (threadIdx.x == 0) {
    pmax[blockIdx.x] = m; psum[blockIdx.x] = s;
    __threadfence();
    lastFlag = (__hip_atomic_fetch_add(counter, 1, __ATOMIC_ACQ_REL,
                                       __HIP_MEMORY_SCOPE_AGENT) == 1023);
  }
  __syncthreads();
  if (!lastFlag) return;
  // final: reduce the 1024 partials (agent-scope loads: cross-XCD safe)
  int t = threadIdx.x;
  float fm = __hip_atomic_load(&pmax[t], __ATOMIC_RELAXED, __HIP_MEMORY_SCOPE_AGENT);
  float fs = __hip_atomic_load(&psum[t], __ATOMIC_RELAXED, __HIP_MEMORY_SCOPE_AGENT);
#pragma unroll
  for (int k = 1; k < 4; ++k) {
    float m2 = __hip_atomic_load(&pmax[t + k * 256], __ATOMIC_RELAXED, __HIP_MEMORY_SCOPE_AGENT);
    float s2 = __hip_atomic_load(&psum[t + k * 256], __ATOMIC_RELAXED, __HIP_MEMORY_SCOPE_AGENT);
    ms_combine(fm, fs, m2, s2);
  }
  ms_block_reduce(fm, fs);
  if (t == 0) { red[0] = fm; red[1] = 1.0f / fs; }
}

// ---------- CSR build ----------
__global__ __launch_bounds__(256) void k_scan_bsum(const int* __restrict__ cnt,
                                                   int* __restrict__ bsum) {
  int i = blockIdx.x * 256 + threadIdx.x;
  int v = (i < NN) ? cnt[i] : 0;
#pragma unroll
  for (int s = 1; s < 64; s <<= 1) v += __shfl_xor(v, s, 64);
  __shared__ int sv[4];
  if ((threadIdx.x & 63) == 0) sv[threadIdx.x >> 6] = v;
  __syncthreads();
  if (threadIdx.x == 0) bsum[blockIdx.x] = sv[0] + sv[1] + sv[2] + sv[3];
}
__global__ __launch_bounds__(512) void k_scan_boff(const int* __restrict__ bsum,
                                                   int* __restrict__ boff,
                                                   int* __restrict__ rowptr) {
  __shared__ int s[512];
  int t = threadIdx.x;
  int v = (t < SCANB) ? bsum[t] : 0;
  s[t] = v;
  __syncthreads();
  for (int off = 1; off < 512; off <<= 1) {
    int u = (t >= off) ? s[t - off] : 0;
    __syncthreads();
    s[t] += u;
    __syncthreads();
  }
  if (t < SCANB) boff[t] = s[t] - v;  // exclusive
  if (t == 0) rowptr[NN] = NE;
}
__global__ __launch_bounds__(256) void k_scan_final(int* __restrict__ cnt,
                                                    const int* __restrict__ boff,
                                                    int* __restrict__ rowptr) {
  __shared__ int s[256];
  int b = blockIdx.x, t = threadIdx.x, i = b * 256 + t;
  int v = (i < NN) ? cnt[i] : 0;
  s[t] = v;
  __syncthreads();
  for (int off = 1; off < 256; off <<= 1) {
    int u = (t >= off) ? s[t - off] : 0;
    __syncthreads();
    s[t] += u;
    __syncthreads();
  }
  int excl = s[t] - v + boff[b];
  if (i < NN) { rowptr[i] = excl; cnt[i] = excl; }  // cnt becomes the fill cursor
}
// fill: perm[e] = CSR slot of edge e
__global__ __launch_bounds__(256) void k_fill(const int* __restrict__ ei,
                                              int* __restrict__ cursor,
                                              int* __restrict__ perm) {
  int e = blockIdx.x * 256 + threadIdx.x;
  if (e >= NE) return;
  int c = ei[NE + e];
  int pos = atomicAdd(&cursor[c], 1);
  perm[e] = pos;
}

extern "C" void kernel_launch(void* const* d_in, const int* in_sizes, int n_in,
                              void* d_out, int out_size, void* d_ws, size_t ws_size,
                              hipStream_t stream) {
  const float* nf  = (const float*)d_in[0];
  const float* ef  = (const float*)d_in[1];
  const float* mW1 = (const float*)d_in[2];
  const float* mb1 = (const float*)d_in[3];
  const float* mW2 = (const float*)d_in[4];
  const float* mb2 = (const float*)d_in[5];
  const float* aW  = (const float*)d_in[6];
  // d_in[7] = a_b — unused (softmax is shift-invariant)
  const float* uW1 = (const float*)d_in[8];
  const float* ub1 = (const float*)d_in[9];
  const float* uW2 = (const float*)d_in[10];
  const float* ub2 = (const float*)d_in[11];
  const int*   ei  = (const int*)d_in[12];
  float* out = (float*)d_out;

  // ws layout (bytes):
  //   0          msg fp8 [NE*128] (CSR order)   76,800,000
  //   76800000   logits f32 [NE]  (CSR order)    2,400,000
  //   79200000   pmax[1024] psum[1024] red[2] counter[1]  8,260
  //   79208260->79208256 base kept: W1p8|W2p8 fp8, U1p|U2p bf16  151,552
  //   79413056   rowptr[NN+1] cnt[NN] perm[NE] bsum boff  3,204,100
  //   82620000   nfb bf16 [NN*128]              25,600,000
  //   108220000  nfb8 fp8 [NN*128]              12,800,000  -> total ~121MB
  char* ws = (char*)d_ws;
  uint8_t* msg8 = (uint8_t*)ws;
  float* logits = (float*)(ws + 76800000);
  float* pmax = (float*)(ws + 79200000);
  float* psum = pmax + 1024;
  float* red  = psum + 1024;
  int* counter = (int*)(red + 2);
  uint8_t* W1p8 = (uint8_t*)(ws + 79208256 + 64);   // shift past counter pad
  uint8_t* W2p8 = W1p8 + 36864;
  short* U1p = (short*)(W2p8 + 16384);
  short* U2p = U1p + 32768;
  int* rowptr = (int*)(ws + 79413056);
  int* cnt    = rowptr + (NN + 1);
  int* perm   = cnt + NN;
  int* bsum   = perm + NE;
  int* boff   = bsum + 512;
  short* nfb  = (short*)(ws + 82620000);
  uint8_t* nfb8 = (uint8_t*)(ws + 108220000);

  k_prep_all<<<400, 256, 0, stream>>>(uW1, uW2, mW1, mW2, U1p, U2p, W1p8, W2p8,
                                      cnt, counter);
  k_prep_nf<<<2048, 256, 0, stream>>>(nf, nfb, nfb8, ei, cnt);
  k_scan_bsum<<<SCANB, 256, 0, stream>>>(cnt, bsum);
  k_scan_boff<<<1, 512, 0, stream>>>(bsum, boff, rowptr);
  k_scan_final<<<SCANB, 256, 0, stream>>>(cnt, boff, rowptr);
  k_fill<<<(NE + 255) / 256, 256, 0, stream>>>(ei, cnt, perm);
  k_edge_mfma<<<NEB, 256, 0, stream>>>(nfb8, ef, W1p8, mb1, W2p8, mb2, aW, ei, perm,
                                       msg8, logits);
  k_red<<<1024, 256, 0, stream>>>(logits, pmax, psum, red, counter);
  k_node_fused<<<(NN + 127) / 128, 256, 0, stream>>>(nfb, msg8, logits, rowptr,
                                                     red, U1p, ub1, U2p, ub2, out);
}

// Round 23
// 314.177 us; speedup vs baseline: 1.1085x; 1.1085x over previous
//
#include <hip/hip_runtime.h>
#include <hip/hip_bf16.h>
#include <hip/hip_fp8.h>
#include <stdint.h>

#define NN 100000
#define NE 600000
#define ND 128
#define ED 32
#define HID 128
#define SCANB 391        // ceil(NN/256)
#define NEB 4688         // ceil(NE/128) edge blocks (tail: 64 rows)

using short8 = __attribute__((ext_vector_type(8))) short;
using f32x4  = __attribute__((ext_vector_type(4))) float;
using f32x2  = __attribute__((ext_vector_type(2))) float;

// ---------- bf16 helpers (manual RNE, deterministic) ----------
__device__ __forceinline__ uint32_t f2bf(float f) {
  uint32_t u = __float_as_uint(f);
  return (u + 0x7FFFu + ((u >> 16) & 1u)) >> 16;
}
__device__ __forceinline__ float bf2f(uint32_t h) {
  return __uint_as_float(h << 16);
}
__device__ __forceinline__ short8 pack8(float4 a, float4 b) {
  short8 s;
  s[0] = (short)f2bf(a.x); s[1] = (short)f2bf(a.y);
  s[2] = (short)f2bf(a.z); s[3] = (short)f2bf(a.w);
  s[4] = (short)f2bf(b.x); s[5] = (short)f2bf(b.y);
  s[6] = (short)f2bf(b.z); s[7] = (short)f2bf(b.w);
  return s;
}

// ---------- fp8 e4m3 helpers (HW cvt on gfx950; header fallback) ----------
__device__ __forceinline__ uint8_t fp8_enc(float v) {
#if __has_builtin(__builtin_amdgcn_cvt_pk_fp8_f32)
  return (uint8_t)(__builtin_amdgcn_cvt_pk_fp8_f32(v, v, 0, false) & 0xFF);
#else
  __hip_fp8_e4m3 q(v);
  return q.__x;
#endif
}
__device__ __forceinline__ float2 fp8_dec2(uint32_t v) {
#if __has_builtin(__builtin_amdgcn_cvt_pk_f32_fp8)
  f32x2 r = __builtin_amdgcn_cvt_pk_f32_fp8((int)v, false);
  return make_float2(r[0], r[1]);
#else
  __hip_fp8_e4m3 qa, qb;
  qa.__x = (uint8_t)(v & 0xFF); qb.__x = (uint8_t)((v >> 8) & 0xFF);
  return make_float2((float)qa, (float)qb);
#endif
}
// pack two float4 into 8 fp8 bytes, returned as the MFMA A-operand long
__device__ __forceinline__ long pack_fp8x8(float4 a, float4 b) {
  union { uint8_t u8[8]; long l; } u;
  u.u8[0] = fp8_enc(a.x); u.u8[1] = fp8_enc(a.y);
  u.u8[2] = fp8_enc(a.z); u.u8[3] = fp8_enc(a.w);
  u.u8[4] = fp8_enc(b.x); u.u8[5] = fp8_enc(b.y);
  u.u8[6] = fp8_enc(b.z); u.u8[7] = fp8_enc(b.w);
  return u.l;
}

// ---------- combined weight pre-pack + cnt/counter zeroing, one launch ----------
__global__ __launch_bounds__(256) void k_prep_all(
    const float* __restrict__ uW1, const float* __restrict__ uW2,
    const float* __restrict__ W1, const float* __restrict__ W2,
    short* __restrict__ U1p, short* __restrict__ U2p,
    uint8_t* __restrict__ W1p8, uint8_t* __restrict__ W2p8,
    int* __restrict__ cnt, int* __restrict__ counter) {
  int o = blockIdx.x * 256 + threadIdx.x;
  if (o < NN) cnt[o] = 0;
  if (o == 0) *counter = 0;
  const float* src; int rel; int isFp8;
  short* dstS = nullptr; uint8_t* dst8 = nullptr;
  if (o < 32768)       { rel = o;         src = uW1; dstS = U1p;  isFp8 = 0; }
  else if (o < 49152)  { rel = o - 32768; src = uW2; dstS = U2p;  isFp8 = 0; }
  else if (o < 86016)  { rel = o - 49152; src = W1;  dst8 = W1p8; isFp8 = 1; }
  else if (o < 102400) { rel = o - 86016; src = W2;  dst8 = W2p8; isFp8 = 1; }
  else return;
  int j = rel & 7, c16 = (rel >> 3) & 15, g = (rel >> 7) & 3, nt = (rel >> 9) & 7, c = rel >> 12;
  int k = c * 32 + g * 8 + j, n = nt * 16 + c16;
  float v = src[k * 128 + n];
  if (isFp8) dst8[rel] = fp8_enc(v);
  else       dstS[rel] = (short)f2bf(v);
}

// ---------- node features fp32 -> bf16 + fp8; fused histogram ----------
__global__ __launch_bounds__(256) void k_prep_nf(const float* __restrict__ nf,
                                                 short* __restrict__ nfb,
                                                 uint8_t* __restrict__ nfb8,
                                                 const int* __restrict__ ei,
                                                 int* __restrict__ cnt) {
  const int total = NN * ND / 8;
  int gid = blockIdx.x * 256 + threadIdx.x;
  for (int e = gid; e < NE; e += gridDim.x * 256)
    atomicAdd(&cnt[ei[NE + e]], 1);
  for (int u = gid; u < total; u += gridDim.x * 256) {
    const float* s = nf + (size_t)u * 8;
    float4 v0 = *(const float4*)s, v1 = *(const float4*)(s + 4);
    *(short8*)(nfb + (size_t)u * 8) = pack8(v0, v1);
    uint8_t b[8];
    b[0] = fp8_enc(v0.x); b[1] = fp8_enc(v0.y); b[2] = fp8_enc(v0.z); b[3] = fp8_enc(v0.w);
    b[4] = fp8_enc(v1.x); b[5] = fp8_enc(v1.y); b[6] = fp8_enc(v1.z); b[7] = fp8_enc(v1.w);
    *(uint2*)(nfb8 + (size_t)u * 8) = *(const uint2*)b;
  }
}

// ---------- edge MLP: full fp8, 128-row tile, 4 blocks/CU (R21, unchanged) ----------
__global__ __launch_bounds__(256, 4) void k_edge_mfma(
    const uint8_t* __restrict__ nfb8, const float* __restrict__ ef,
    const uint8_t* __restrict__ W1p8, const float* __restrict__ b1,
    const uint8_t* __restrict__ W2p8, const float* __restrict__ b2,
    const float* __restrict__ aW, const int* __restrict__ ei,
    const int* __restrict__ perm,
    uint8_t* __restrict__ msg8, float* __restrict__ logits) {
  __shared__ __align__(16) uint8_t sRow[128 * 136];
  __shared__ __align__(16) uint8_t sCol[128 * 136];
  __shared__ __align__(16) uint8_t sB8[4096];
  __shared__ int sIdx[256];
  __shared__ int sPerm[128];

  const int tid = threadIdx.x;
  const int wv = tid >> 6, ln = tid & 63, cr = ln & 15, gp = ln >> 4;
  const int e0 = blockIdx.x * 128;
  const int wrow = wv * 32;

  if (tid < 128) {
    int e = e0 + tid; if (e >= NE) e = NE - 1;
    sIdx[tid] = ei[e];
    sIdx[128 + tid] = ei[NE + e];
    sPerm[tid] = perm[e];
  }
  __syncthreads();

  // single gather pass: both endpoint rows, full 128B lines
#pragma unroll
  for (int it = 0; it < 16; ++it) {
    int t = it * 256 + tid;
    int side = t >> 11;
    int r = (t & 2047) >> 4;
    int o = (t & 15) * 8;
    const uint8_t* src = nfb8 + (size_t)sIdx[side * 128 + r] * ND + o;
    uint8_t* dst = (side ? sCol : sRow) + r * 136 + o;
    *(uint2*)dst = *(const uint2*)src;
  }

  // ef chunk (c==8) operands: direct global reads, packed in-register
  long efA0, efA1;
  {
    int ea = e0 + wrow + cr;      if (ea >= NE) ea = NE - 1;
    int eb = e0 + wrow + 16 + cr; if (eb >= NE) eb = NE - 1;
    const float* f0 = ef + (size_t)ea * ED + gp * 8;
    const float* f1 = ef + (size_t)eb * ED + gp * 8;
    efA0 = pack_fp8x8(*(const float4*)f0, *(const float4*)(f0 + 4));
    efA1 = pack_fp8x8(*(const float4*)f1, *(const float4*)(f1 + 4));
  }

  float bia[8], aWr[8], bia2[8];
#pragma unroll
  for (int nt = 0; nt < 8; ++nt) {
    bia[nt] = b1[nt * 16 + cr];
    bia2[nt] = b2[nt * 16 + cr];
    aWr[nt] = aW[nt * 16 + cr];
  }
  f32x4 acc[2][8];
#pragma unroll
  for (int mt = 0; mt < 2; ++mt)
#pragma unroll
    for (int nt = 0; nt < 8; ++nt)
      acc[mt][nt] = (f32x4){bia[nt], bia[nt], bia[nt], bia[nt]};

  // layer 1: 9 fp8 chunks, single-buffered sB (2 barriers/chunk)
  for (int c = 0; c < 9; ++c) {
    __syncthreads();
    *(uint4*)&sB8[tid * 16] = *(const uint4*)(W1p8 + c * 4096 + tid * 16);
    __syncthreads();
    long af0, af1;
    if (c < 8) {
      const uint8_t* aSrc = (c < 4) ? (sRow + c * 32) : (sCol + (c - 4) * 32);
      af0 = *(const long*)(aSrc + (wrow + cr) * 136 + gp * 8);
      af1 = *(const long*)(aSrc + (wrow + 16 + cr) * 136 + gp * 8);
    } else {
      af0 = efA0; af1 = efA1;
    }
#pragma unroll
    for (int nt = 0; nt < 8; ++nt) {
      long bfr = *(const long*)&sB8[(nt * 4 + gp) * 128 + cr * 8];
      acc[0][nt] = __builtin_amdgcn_mfma_f32_16x16x32_fp8_fp8(af0, bfr, acc[0][nt], 0, 0, 0);
      acc[1][nt] = __builtin_amdgcn_mfma_f32_16x16x32_fp8_fp8(af1, bfr, acc[1][nt], 0, 0, 0);
    }
  }

  // relu(h) -> fp8 into sRow (wave-private rows)
#pragma unroll
  for (int mt = 0; mt < 2; ++mt)
#pragma unroll
    for (int nt = 0; nt < 8; ++nt)
#pragma unroll
      for (int rr = 0; rr < 4; ++rr)
        sRow[(wrow + mt * 16 + gp * 4 + rr) * 136 + nt * 16 + cr] =
            fp8_enc(fmaxf(acc[mt][nt][rr], 0.f));

  // layer 2: 4 fp8 chunks, single-buffered sB
  f32x4 acc2[2][8];
#pragma unroll
  for (int mt = 0; mt < 2; ++mt)
#pragma unroll
    for (int nt = 0; nt < 8; ++nt)
      acc2[mt][nt] = (f32x4){bia2[nt], bia2[nt], bia2[nt], bia2[nt]};
  for (int c2 = 0; c2 < 4; ++c2) {
    __syncthreads();
    *(uint4*)&sB8[tid * 16] = *(const uint4*)(W2p8 + c2 * 4096 + tid * 16);
    __syncthreads();
    long af0 = *(const long*)&sRow[(wrow + cr) * 136 + c2 * 32 + gp * 8];
    long af1 = *(const long*)&sRow[(wrow + 16 + cr) * 136 + c2 * 32 + gp * 8];
#pragma unroll
    for (int nt = 0; nt < 8; ++nt) {
      long bfr = *(const long*)&sB8[(nt * 4 + gp) * 128 + cr * 8];
      acc2[0][nt] = __builtin_amdgcn_mfma_f32_16x16x32_fp8_fp8(af0, bfr, acc2[0][nt], 0, 0, 0);
      acc2[1][nt] = __builtin_amdgcn_mfma_f32_16x16x32_fp8_fp8(af1, bfr, acc2[1][nt], 0, 0, 0);
    }
  }

  // attention logits -> CSR slot (guarded for tail)
#pragma unroll
  for (int mt = 0; mt < 2; ++mt)
#pragma unroll
    for (int rr = 0; rr < 4; ++rr) {
      float p = 0.f;
#pragma unroll
      for (int nt = 0; nt < 8; ++nt) p += acc2[mt][nt][rr] * aWr[nt];
      p += __shfl_xor(p, 1, 64);
      p += __shfl_xor(p, 2, 64);
      p += __shfl_xor(p, 4, 64);
      p += __shfl_xor(p, 8, 64);
      int row = wrow + mt * 16 + gp * 4 + rr;
      if (cr == 0 && e0 + row < NE) logits[sPerm[row]] = p;
    }

  // messages -> sCol (fp8) -> 128B rows scattered to CSR slots (guarded)
#pragma unroll
  for (int mt = 0; mt < 2; ++mt)
#pragma unroll
    for (int nt = 0; nt < 8; ++nt)
#pragma unroll
      for (int rr = 0; rr < 4; ++rr)
        sCol[(wrow + mt * 16 + gp * 4 + rr) * 136 + nt * 16 + cr] =
            fp8_enc(acc2[mt][nt][rr]);
  __syncthreads();
#pragma unroll
  for (int it = 0; it < 8; ++it) {
    int row = it * 16 + (tid >> 4), o8 = (tid & 15) * 8;
    if (e0 + row < NE)
      *(uint2*)(msg8 + (size_t)sPerm[row] * HID + o8) = *(const uint2*)&sCol[row * 136 + o8];
  }
}

// ---------- node update MLP: barrier-free direct-operand (R21, proven) ----------
__global__ __launch_bounds__(256, 4) void k_node_mfma(
    const short* __restrict__ nfb, const short* __restrict__ aggb,
    const short* __restrict__ U1p, const float* __restrict__ b1,
    const short* __restrict__ U2p, const float* __restrict__ b2,
    float* __restrict__ out) {
  __shared__ __align__(16) short sH[128 * 136];  // 34816 B -> 4 blocks/CU

  const int tid = threadIdx.x;
  const int wv = tid >> 6, ln = tid & 63, cr = ln & 15, gp = ln >> 4;
  const int n0 = blockIdx.x * 128;
  const int wrow = wv * 32;

  int na0 = n0 + wrow + cr;      if (na0 >= NN) na0 = NN - 1;
  int na1 = n0 + wrow + 16 + cr; if (na1 >= NN) na1 = NN - 1;

  float bia[8], bia2[8];
#pragma unroll
  for (int nt = 0; nt < 8; ++nt) {
    bia[nt] = b1[nt * 16 + cr];
    bia2[nt] = b2[nt * 16 + cr];
  }
  f32x4 acc[2][8];
#pragma unroll
  for (int mt = 0; mt < 2; ++mt)
#pragma unroll
    for (int nt = 0; nt < 8; ++nt)
      acc[mt][nt] = (f32x4){bia[nt], bia[nt], bia[nt], bia[nt]};

#pragma unroll
  for (int c = 0; c < 8; ++c) {
    const short* base = (c < 4) ? nfb : aggb;
    const int ko = (c & 3) * 32 + gp * 8;
    short8 af0 = *(const short8*)(base + (size_t)na0 * ND + ko);
    short8 af1 = *(const short8*)(base + (size_t)na1 * ND + ko);
    const short* Wc = U1p + c * 4096;
#pragma unroll
    for (int nt = 0; nt < 8; ++nt) {
      short8 bfr = *(const short8*)(Wc + (nt * 4 + gp) * 128 + cr * 8);
      acc[0][nt] = __builtin_amdgcn_mfma_f32_16x16x32_bf16(af0, bfr, acc[0][nt], 0, 0, 0);
      acc[1][nt] = __builtin_amdgcn_mfma_f32_16x16x32_bf16(af1, bfr, acc[1][nt], 0, 0, 0);
    }
  }

#pragma unroll
  for (int mt = 0; mt < 2; ++mt)
#pragma unroll
    for (int nt = 0; nt < 8; ++nt)
#pragma unroll
      for (int rr = 0; rr < 4; ++rr)
        sH[(wrow + mt * 16 + gp * 4 + rr) * 136 + nt * 16 + cr] =
            (short)f2bf(fmaxf(acc[mt][nt][rr], 0.f));

  f32x4 acc2[2][8];
#pragma unroll
  for (int mt = 0; mt < 2; ++mt)
#pragma unroll
    for (int nt = 0; nt < 8; ++nt)
      acc2[mt][nt] = (f32x4){bia2[nt], bia2[nt], bia2[nt], bia2[nt]};
#pragma unroll
  for (int c2 = 0; c2 < 4; ++c2) {
    short8 af0 = *(const short8*)&sH[(wrow + cr) * 136 + c2 * 32 + gp * 8];
    short8 af1 = *(const short8*)&sH[(wrow + 16 + cr) * 136 + c2 * 32 + gp * 8];
    const short* Wc = U2p + c2 * 4096;
#pragma unroll
    for (int nt = 0; nt < 8; ++nt) {
      short8 bfr = *(const short8*)(Wc + (nt * 4 + gp) * 128 + cr * 8);
      acc2[0][nt] = __builtin_amdgcn_mfma_f32_16x16x32_bf16(af0, bfr, acc2[0][nt], 0, 0, 0);
      acc2[1][nt] = __builtin_amdgcn_mfma_f32_16x16x32_bf16(af1, bfr, acc2[1][nt], 0, 0, 0);
    }
  }

#pragma unroll
  for (int mt = 0; mt < 2; ++mt)
#pragma unroll
    for (int rr = 0; rr < 4; ++rr) {
      int n = n0 + wrow + mt * 16 + gp * 4 + rr;
      if (n < NN) {
#pragma unroll
        for (int nt = 0; nt < 8; ++nt) {
          int col = nt * 16 + cr;
          float r = bf2f((uint16_t)nfb[(size_t)n * ND + col]);
          out[(size_t)n * ND + col] = acc2[mt][nt][rr] + r;
        }
      }
    }
}

// ---------- fused online softmax reduction: partials + last-block final ----------
__device__ __forceinline__ void ms_combine(float& m, float& s, float m2, float s2) {
  float M = fmaxf(m, m2);
  s = s * expf(m - M) + s2 * expf(m2 - M);
  m = M;
}
__device__ __forceinline__ void ms_block_reduce(float& m, float& s) {
#pragma unroll
  for (int o = 1; o < 64; o <<= 1) {
    float m2 = __shfl_xor(m, o, 64), s2 = __shfl_xor(s, o, 64);
    ms_combine(m, s, m2, s2);
  }
  __shared__ float sm[4], ss[4];
  if ((threadIdx.x & 63) == 0) { sm[threadIdx.x >> 6] = m; ss[threadIdx.x >> 6] = s; }
  __syncthreads();
  m = sm[0]; s = ss[0];
  ms_combine(m, s, sm[1], ss[1]);
  ms_combine(m, s, sm[2], ss[2]);
  ms_combine(m, s, sm[3], ss[3]);
}
__global__ __launch_bounds__(256) void k_red(const float* __restrict__ logits,
                                             float* __restrict__ pmax,
                                             float* __restrict__ psum,
                                             float* __restrict__ red,
                                             int* __restrict__ counter) {
  float m = -3.402823466e38f, s = 0.f;
  for (int i = blockIdx.x * 256 + threadIdx.x; i < NE; i += 1024 * 256) {
    float l = logits[i];
    if (l <= m) s += expf(l - m);
    else { s = s * expf(m - l) + 1.f; m = l; }
  }
  ms_block_reduce(m, s);
  __shared__ int lastFlag;
  if (threadIdx.x == 0) {
    pmax[blockIdx.x] = m; psum[blockIdx.x] = s;
    __threadfence();
    lastFlag = (__hip_atomic_fetch_add(counter, 1, __ATOMIC_ACQ_REL,
                                       __HIP_MEMORY_SCOPE_AGENT) == 1023);
  }
  __syncthreads();
  if (!lastFlag) return;
  int t = threadIdx.x;
  float fm = __hip_atomic_load(&pmax[t], __ATOMIC_RELAXED, __HIP_MEMORY_SCOPE_AGENT);
  float fs = __hip_atomic_load(&psum[t], __ATOMIC_RELAXED, __HIP_MEMORY_SCOPE_AGENT);
#pragma unroll
  for (int k = 1; k < 4; ++k) {
    float m2 = __hip_atomic_load(&pmax[t + k * 256], __ATOMIC_RELAXED, __HIP_MEMORY_SCOPE_AGENT);
    float s2 = __hip_atomic_load(&psum[t + k * 256], __ATOMIC_RELAXED, __HIP_MEMORY_SCOPE_AGENT);
    ms_combine(fm, fs, m2, s2);
  }
  ms_block_reduce(fm, fs);
  if (t == 0) { red[0] = fm; red[1] = 1.0f / fs; }
}

// ---------- CSR build ----------
__global__ __launch_bounds__(256) void k_scan_bsum(const int* __restrict__ cnt,
                                                   int* __restrict__ bsum) {
  int i = blockIdx.x * 256 + threadIdx.x;
  int v = (i < NN) ? cnt[i] : 0;
#pragma unroll
  for (int s = 1; s < 64; s <<= 1) v += __shfl_xor(v, s, 64);
  __shared__ int sv[4];
  if ((threadIdx.x & 63) == 0) sv[threadIdx.x >> 6] = v;
  __syncthreads();
  if (threadIdx.x == 0) bsum[blockIdx.x] = sv[0] + sv[1] + sv[2] + sv[3];
}
__global__ __launch_bounds__(512) void k_scan_boff(const int* __restrict__ bsum,
                                                   int* __restrict__ boff,
                                                   int* __restrict__ rowptr) {
  __shared__ int s[512];
  int t = threadIdx.x;
  int v = (t < SCANB) ? bsum[t] : 0;
  s[t] = v;
  __syncthreads();
  for (int off = 1; off < 512; off <<= 1) {
    int u = (t >= off) ? s[t - off] : 0;
    __syncthreads();
    s[t] += u;
    __syncthreads();
  }
  if (t < SCANB) boff[t] = s[t] - v;  // exclusive
  if (t == 0) rowptr[NN] = NE;
}
__global__ __launch_bounds__(256) void k_scan_final(int* __restrict__ cnt,
                                                    const int* __restrict__ boff,
                                                    int* __restrict__ rowptr) {
  __shared__ int s[256];
  int b = blockIdx.x, t = threadIdx.x, i = b * 256 + t;
  int v = (i < NN) ? cnt[i] : 0;
  s[t] = v;
  __syncthreads();
  for (int off = 1; off < 256; off <<= 1) {
    int u = (t >= off) ? s[t - off] : 0;
    __syncthreads();
    s[t] += u;
    __syncthreads();
  }
  int excl = s[t] - v + boff[b];
  if (i < NN) { rowptr[i] = excl; cnt[i] = excl; }  // cnt becomes the fill cursor
}
// fill: perm[e] = CSR slot of edge e
__global__ __launch_bounds__(256) void k_fill(const int* __restrict__ ei,
                                              int* __restrict__ cursor,
                                              int* __restrict__ perm) {
  int e = blockIdx.x * 256 + threadIdx.x;
  if (e >= NE) return;
  int c = ei[NE + e];
  int pos = atomicAdd(&cursor[c], 1);
  perm[e] = pos;
}

// ---------- CSR aggregate: streaming, writes bf16 agg (R21, proven) ----------
__global__ __launch_bounds__(256) void k_agg(
    const uint8_t* __restrict__ msg8, const float* __restrict__ logits,
    const int* __restrict__ rowptr, const float* __restrict__ red,
    short* __restrict__ aggb) {
  int n = blockIdx.x * 4 + (threadIdx.x >> 6);
  int lane = threadIdx.x & 63;
  if (n >= NN) return;
  float gm = red[0], inv = red[1];
  int i0 = rowptr[n], i1 = rowptr[n + 1];
  float a0 = 0.f, a1 = 0.f;
  for (int i = i0; i < i1; ++i) {
    float wt = expf(logits[i] - gm) * inv;
    uint32_t pk = *(const uint16_t*)(msg8 + (size_t)i * HID + lane * 2);
    float2 d = fp8_dec2(pk);
    a0 += wt * d.x;
    a1 += wt * d.y;
  }
  uint32_t packed = f2bf(a0) | (f2bf(a1) << 16);
  *(uint32_t*)(aggb + (size_t)n * ND + lane * 2) = packed;
}

extern "C" void kernel_launch(void* const* d_in, const int* in_sizes, int n_in,
                              void* d_out, int out_size, void* d_ws, size_t ws_size,
                              hipStream_t stream) {
  const float* nf  = (const float*)d_in[0];
  const float* ef  = (const float*)d_in[1];
  const float* mW1 = (const float*)d_in[2];
  const float* mb1 = (const float*)d_in[3];
  const float* mW2 = (const float*)d_in[4];
  const float* mb2 = (const float*)d_in[5];
  const float* aW  = (const float*)d_in[6];
  // d_in[7] = a_b — unused (softmax is shift-invariant)
  const float* uW1 = (const float*)d_in[8];
  const float* ub1 = (const float*)d_in[9];
  const float* uW2 = (const float*)d_in[10];
  const float* ub2 = (const float*)d_in[11];
  const int*   ei  = (const int*)d_in[12];
  float* out = (float*)d_out;

  // ws layout (bytes):
  //   0          msg fp8 [NE*128] (CSR order)   76,800,000
  //   76800000   logits f32 [NE]  (CSR order)    2,400,000
  //   79200000   pmax[1024] psum[1024] red[2] counter[1] (+pad)
  //   79208320   W1p8|W2p8 fp8, U1p|U2p bf16       151,552
  //   79413056   rowptr[NN+1] cnt[NN] perm[NE] bsum boff  3,204,100
  //   82620000   nfb bf16 [NN*128]              25,600,000
  //   108220000  nfb8 fp8 [NN*128]              12,800,000
  //   121020000  aggb bf16 [NN*128]             25,600,000  -> total ~146.6MB
  char* ws = (char*)d_ws;
  uint8_t* msg8 = (uint8_t*)ws;
  float* logits = (float*)(ws + 76800000);
  float* pmax = (float*)(ws + 79200000);
  float* psum = pmax + 1024;
  float* red  = psum + 1024;
  int* counter = (int*)(red + 2);
  uint8_t* W1p8 = (uint8_t*)(ws + 79208320);
  uint8_t* W2p8 = W1p8 + 36864;
  short* U1p = (short*)(W2p8 + 16384);
  short* U2p = U1p + 32768;
  int* rowptr = (int*)(ws + 79413056);
  int* cnt    = rowptr + (NN + 1);
  int* perm   = cnt + NN;
  int* bsum   = perm + NE;
  int* boff   = bsum + 512;
  short* nfb  = (short*)(ws + 82620000);
  uint8_t* nfb8 = (uint8_t*)(ws + 108220000);
  short* aggb = (short*)(ws + 121020000);

  k_prep_all<<<400, 256, 0, stream>>>(uW1, uW2, mW1, mW2, U1p, U2p, W1p8, W2p8,
                                      cnt, counter);
  k_prep_nf<<<2048, 256, 0, stream>>>(nf, nfb, nfb8, ei, cnt);
  k_scan_bsum<<<SCANB, 256, 0, stream>>>(cnt, bsum);
  k_scan_boff<<<1, 512, 0, stream>>>(bsum, boff, rowptr);
  k_scan_final<<<SCANB, 256, 0, stream>>>(cnt, boff, rowptr);
  k_fill<<<(NE + 255) / 256, 256, 0, stream>>>(ei, cnt, perm);
  k_edge_mfma<<<NEB, 256, 0, stream>>>(nfb8, ef, W1p8, mb1, W2p8, mb2, aW, ei, perm,
                                       msg8, logits);
  k_red<<<1024, 256, 0, stream>>>(logits, pmax, psum, red, counter);
  k_agg<<<(NN + 3) / 4, 256, 0, stream>>>(msg8, logits, rowptr, red, aggb);
  k_node_mfma<<<(NN + 127) / 128, 256, 0, stream>>>(nfb, aggb, U1p, ub1, U2p, ub2, out);
}

// Round 24
// 294.748 us; speedup vs baseline: 1.1816x; 1.0659x over previous
//
#include <hip/hip_runtime.h>
#include <hip/hip_bf16.h>
#include <hip/hip_fp8.h>
#include <stdint.h>

#define NN 100000
#define NE 600000
#define ND 128
#define ED 32
#define HID 128
#define SCANB 391        // ceil(NN/256)
#define NEB 4688         // ceil(NE/128) edge blocks (tail: 64 rows)

using short8 = __attribute__((ext_vector_type(8))) short;
using f32x4  = __attribute__((ext_vector_type(4))) float;
using f32x2  = __attribute__((ext_vector_type(2))) float;

// ---------- bf16 helpers (manual RNE, deterministic) ----------
__device__ __forceinline__ uint32_t f2bf(float f) {
  uint32_t u = __float_as_uint(f);
  return (u + 0x7FFFu + ((u >> 16) & 1u)) >> 16;
}
__device__ __forceinline__ float bf2f(uint32_t h) {
  return __uint_as_float(h << 16);
}
__device__ __forceinline__ short8 pack8(float4 a, float4 b) {
  short8 s;
  s[0] = (short)f2bf(a.x); s[1] = (short)f2bf(a.y);
  s[2] = (short)f2bf(a.z); s[3] = (short)f2bf(a.w);
  s[4] = (short)f2bf(b.x); s[5] = (short)f2bf(b.y);
  s[6] = (short)f2bf(b.z); s[7] = (short)f2bf(b.w);
  return s;
}

// ---------- fp8 e4m3 helpers (HW cvt on gfx950; header fallback) ----------
__device__ __forceinline__ uint8_t fp8_enc(float v) {
#if __has_builtin(__builtin_amdgcn_cvt_pk_fp8_f32)
  return (uint8_t)(__builtin_amdgcn_cvt_pk_fp8_f32(v, v, 0, false) & 0xFF);
#else
  __hip_fp8_e4m3 q(v);
  return q.__x;
#endif
}
__device__ __forceinline__ float2 fp8_dec2(uint32_t v) {
#if __has_builtin(__builtin_amdgcn_cvt_pk_f32_fp8)
  f32x2 r = __builtin_amdgcn_cvt_pk_f32_fp8((int)v, false);
  return make_float2(r[0], r[1]);
#else
  __hip_fp8_e4m3 qa, qb;
  qa.__x = (uint8_t)(v & 0xFF); qb.__x = (uint8_t)((v >> 8) & 0xFF);
  return make_float2((float)qa, (float)qb);
#endif
}
// pack two float4 into 8 fp8 bytes, returned as the MFMA A-operand long
__device__ __forceinline__ long pack_fp8x8(float4 a, float4 b) {
  union { uint8_t u8[8]; long l; } u;
  u.u8[0] = fp8_enc(a.x); u.u8[1] = fp8_enc(a.y);
  u.u8[2] = fp8_enc(a.z); u.u8[3] = fp8_enc(a.w);
  u.u8[4] = fp8_enc(b.x); u.u8[5] = fp8_enc(b.y);
  u.u8[6] = fp8_enc(b.z); u.u8[7] = fp8_enc(b.w);
  return u.l;
}

// ---------- combined weight pre-pack: node bf16 + edge fp8, one launch ----------
__global__ __launch_bounds__(256) void k_prep_all(
    const float* __restrict__ uW1, const float* __restrict__ uW2,
    const float* __restrict__ W1, const float* __restrict__ W2,
    short* __restrict__ U1p, short* __restrict__ U2p,
    uint8_t* __restrict__ W1p8, uint8_t* __restrict__ W2p8) {
  int o = blockIdx.x * 256 + threadIdx.x;
  const float* src; int rel; int isFp8;
  short* dstS = nullptr; uint8_t* dst8 = nullptr;
  if (o < 32768)       { rel = o;         src = uW1; dstS = U1p;  isFp8 = 0; }
  else if (o < 49152)  { rel = o - 32768; src = uW2; dstS = U2p;  isFp8 = 0; }
  else if (o < 86016)  { rel = o - 49152; src = W1;  dst8 = W1p8; isFp8 = 1; }
  else if (o < 102400) { rel = o - 86016; src = W2;  dst8 = W2p8; isFp8 = 1; }
  else return;
  int j = rel & 7, c16 = (rel >> 3) & 15, g = (rel >> 7) & 3, nt = (rel >> 9) & 7, c = rel >> 12;
  int k = c * 32 + g * 8 + j, n = nt * 16 + c16;
  float v = src[k * 128 + n];
  if (isFp8) dst8[rel] = fp8_enc(v);
  else       dstS[rel] = (short)f2bf(v);
}

// ---------- node features fp32 -> bf16 + fp8; also zeroes cnt ----------
__global__ __launch_bounds__(256) void k_prep_nf(const float* __restrict__ nf,
                                                 short* __restrict__ nfb,
                                                 uint8_t* __restrict__ nfb8,
                                                 int* __restrict__ cnt) {
  const int total = NN * ND / 8;
  int gid = blockIdx.x * 256 + threadIdx.x;
  for (int i = gid; i < NN; i += gridDim.x * 256) cnt[i] = 0;
  for (int u = gid; u < total; u += gridDim.x * 256) {
    const float* s = nf + (size_t)u * 8;
    float4 v0 = *(const float4*)s, v1 = *(const float4*)(s + 4);
    *(short8*)(nfb + (size_t)u * 8) = pack8(v0, v1);
    uint8_t b[8];
    b[0] = fp8_enc(v0.x); b[1] = fp8_enc(v0.y); b[2] = fp8_enc(v0.z); b[3] = fp8_enc(v0.w);
    b[4] = fp8_enc(v1.x); b[5] = fp8_enc(v1.y); b[6] = fp8_enc(v1.z); b[7] = fp8_enc(v1.w);
    *(uint2*)(nfb8 + (size_t)u * 8) = *(const uint2*)b;
  }
}

// ---------- edge MLP: full fp8, 128-row tile, 4 blocks/CU ----------
// LDS 40448B (<= 160KB/4): ef packed in-register for chunk 8, sB single-buffered.
__global__ __launch_bounds__(256, 4) void k_edge_mfma(
    const uint8_t* __restrict__ nfb8, const float* __restrict__ ef,
    const uint8_t* __restrict__ W1p8, const float* __restrict__ b1,
    const uint8_t* __restrict__ W2p8, const float* __restrict__ b2,
    const float* __restrict__ aW, const int* __restrict__ ei,
    const int* __restrict__ perm,
    uint8_t* __restrict__ msg8, float* __restrict__ logits) {
  __shared__ __align__(16) uint8_t sRow[128 * 136];  // 17408
  __shared__ __align__(16) uint8_t sCol[128 * 136];  // 17408
  __shared__ __align__(16) uint8_t sB8[4096];        //  4096
  __shared__ int sIdx[256];                          //  1024
  __shared__ int sPerm[128];                         //   512  -> 40448 total

  const int tid = threadIdx.x;
  const int wv = tid >> 6, ln = tid & 63, cr = ln & 15, gp = ln >> 4;
  const int e0 = blockIdx.x * 128;   // grid NEB; last block has 64 valid rows
  const int wrow = wv * 32;

  if (tid < 128) {
    int e = e0 + tid; if (e >= NE) e = NE - 1;
    sIdx[tid] = ei[e];
    sIdx[128 + tid] = ei[NE + e];
    sPerm[tid] = perm[e];
  }
  __syncthreads();

  // single gather pass: both endpoint rows, full 128B lines
#pragma unroll
  for (int it = 0; it < 16; ++it) {
    int t = it * 256 + tid;
    int side = t >> 11;
    int r = (t & 2047) >> 4;
    int o = (t & 15) * 8;
    const uint8_t* src = nfb8 + (size_t)sIdx[side * 128 + r] * ND + o;
    uint8_t* dst = (side ? sCol : sRow) + r * 136 + o;
    *(uint2*)dst = *(const uint2*)src;
  }

  // ef chunk (c==8) operands: direct global reads, packed in-register
  long efA0, efA1;
  {
    int ea = e0 + wrow + cr;      if (ea >= NE) ea = NE - 1;
    int eb = e0 + wrow + 16 + cr; if (eb >= NE) eb = NE - 1;
    const float* f0 = ef + (size_t)ea * ED + gp * 8;
    const float* f1 = ef + (size_t)eb * ED + gp * 8;
    efA0 = pack_fp8x8(*(const float4*)f0, *(const float4*)(f0 + 4));
    efA1 = pack_fp8x8(*(const float4*)f1, *(const float4*)(f1 + 4));
  }

  float bia[8], aWr[8], bia2[8];
#pragma unroll
  for (int nt = 0; nt < 8; ++nt) {
    bia[nt] = b1[nt * 16 + cr];
    bia2[nt] = b2[nt * 16 + cr];
    aWr[nt] = aW[nt * 16 + cr];
  }
  f32x4 acc[2][8];
#pragma unroll
  for (int mt = 0; mt < 2; ++mt)
#pragma unroll
    for (int nt = 0; nt < 8; ++nt)
      acc[mt][nt] = (f32x4){bia[nt], bia[nt], bia[nt], bia[nt]};

  // ---- layer 1: 9 fp8 chunks, single-buffered sB (2 barriers/chunk) ----
  for (int c = 0; c < 9; ++c) {
    __syncthreads();  // (c=0: gather done) / prior MFMAs done reading sB
    *(uint4*)&sB8[tid * 16] = *(const uint4*)(W1p8 + c * 4096 + tid * 16);
    __syncthreads();
    long af0, af1;
    if (c < 8) {
      const uint8_t* aSrc = (c < 4) ? (sRow + c * 32) : (sCol + (c - 4) * 32);
      af0 = *(const long*)(aSrc + (wrow + cr) * 136 + gp * 8);
      af1 = *(const long*)(aSrc + (wrow + 16 + cr) * 136 + gp * 8);
    } else {
      af0 = efA0; af1 = efA1;
    }
#pragma unroll
    for (int nt = 0; nt < 8; ++nt) {
      long bfr = *(const long*)&sB8[(nt * 4 + gp) * 128 + cr * 8];
      acc[0][nt] = __builtin_amdgcn_mfma_f32_16x16x32_fp8_fp8(af0, bfr, acc[0][nt], 0, 0, 0);
      acc[1][nt] = __builtin_amdgcn_mfma_f32_16x16x32_fp8_fp8(af1, bfr, acc[1][nt], 0, 0, 0);
    }
  }

  // relu(h) -> fp8 into sRow (wave-private rows; in-wave ordering suffices)
#pragma unroll
  for (int mt = 0; mt < 2; ++mt)
#pragma unroll
    for (int nt = 0; nt < 8; ++nt)
#pragma unroll
      for (int rr = 0; rr < 4; ++rr)
        sRow[(wrow + mt * 16 + gp * 4 + rr) * 136 + nt * 16 + cr] =
            fp8_enc(fmaxf(acc[mt][nt][rr], 0.f));

  // ---- layer 2: 4 fp8 chunks, single-buffered sB ----
  f32x4 acc2[2][8];
#pragma unroll
  for (int mt = 0; mt < 2; ++mt)
#pragma unroll
    for (int nt = 0; nt < 8; ++nt)
      acc2[mt][nt] = (f32x4){bia2[nt], bia2[nt], bia2[nt], bia2[nt]};
  for (int c2 = 0; c2 < 4; ++c2) {
    __syncthreads();
    *(uint4*)&sB8[tid * 16] = *(const uint4*)(W2p8 + c2 * 4096 + tid * 16);
    __syncthreads();
    long af0 = *(const long*)&sRow[(wrow + cr) * 136 + c2 * 32 + gp * 8];
    long af1 = *(const long*)&sRow[(wrow + 16 + cr) * 136 + c2 * 32 + gp * 8];
#pragma unroll
    for (int nt = 0; nt < 8; ++nt) {
      long bfr = *(const long*)&sB8[(nt * 4 + gp) * 128 + cr * 8];
      acc2[0][nt] = __builtin_amdgcn_mfma_f32_16x16x32_fp8_fp8(af0, bfr, acc2[0][nt], 0, 0, 0);
      acc2[1][nt] = __builtin_amdgcn_mfma_f32_16x16x32_fp8_fp8(af1, bfr, acc2[1][nt], 0, 0, 0);
    }
  }

  // attention logits -> CSR slot (guarded for tail)
#pragma unroll
  for (int mt = 0; mt < 2; ++mt)
#pragma unroll
    for (int rr = 0; rr < 4; ++rr) {
      float p = 0.f;
#pragma unroll
      for (int nt = 0; nt < 8; ++nt) p += acc2[mt][nt][rr] * aWr[nt];
      p += __shfl_xor(p, 1, 64);
      p += __shfl_xor(p, 2, 64);
      p += __shfl_xor(p, 4, 64);
      p += __shfl_xor(p, 8, 64);
      int row = wrow + mt * 16 + gp * 4 + rr;
      if (cr == 0 && e0 + row < NE) logits[sPerm[row]] = p;
    }

  // messages -> sCol (fp8) -> 128B rows scattered to CSR slots (guarded)
#pragma unroll
  for (int mt = 0; mt < 2; ++mt)
#pragma unroll
    for (int nt = 0; nt < 8; ++nt)
#pragma unroll
      for (int rr = 0; rr < 4; ++rr)
        sCol[(wrow + mt * 16 + gp * 4 + rr) * 136 + nt * 16 + cr] =
            fp8_enc(acc2[mt][nt][rr]);
  __syncthreads();
#pragma unroll
  for (int it = 0; it < 8; ++it) {
    int row = it * 16 + (tid >> 4), o8 = (tid & 15) * 8;
    if (e0 + row < NE)
      *(uint2*)(msg8 + (size_t)sPerm[row] * HID + o8) = *(const uint2*)&sCol[row * 136 + o8];
  }
}

// ---------- node update MLP: barrier-free direct-operand, 128-tile, 4 blk/CU ----------
__global__ __launch_bounds__(256, 4) void k_node_mfma(
    const short* __restrict__ nfb, const short* __restrict__ aggb,
    const short* __restrict__ U1p, const float* __restrict__ b1,
    const short* __restrict__ U2p, const float* __restrict__ b2,
    float* __restrict__ out) {
  __shared__ __align__(16) short sH[128 * 136];  // 34816 B -> 4 blocks/CU

  const int tid = threadIdx.x;
  const int wv = tid >> 6, ln = tid & 63, cr = ln & 15, gp = ln >> 4;
  const int n0 = blockIdx.x * 128;
  const int wrow = wv * 32;

  int na0 = n0 + wrow + cr;      if (na0 >= NN) na0 = NN - 1;
  int na1 = n0 + wrow + 16 + cr; if (na1 >= NN) na1 = NN - 1;

  float bia[8], bia2[8];
#pragma unroll
  for (int nt = 0; nt < 8; ++nt) {
    bia[nt] = b1[nt * 16 + cr];
    bia2[nt] = b2[nt * 16 + cr];
  }
  f32x4 acc[2][8];
#pragma unroll
  for (int mt = 0; mt < 2; ++mt)
#pragma unroll
    for (int nt = 0; nt < 8; ++nt)
      acc[mt][nt] = (f32x4){bia[nt], bia[nt], bia[nt], bia[nt]};

#pragma unroll
  for (int c = 0; c < 8; ++c) {
    const short* base = (c < 4) ? nfb : aggb;
    const int ko = (c & 3) * 32 + gp * 8;
    short8 af0 = *(const short8*)(base + (size_t)na0 * ND + ko);
    short8 af1 = *(const short8*)(base + (size_t)na1 * ND + ko);
    const short* Wc = U1p + c * 4096;
#pragma unroll
    for (int nt = 0; nt < 8; ++nt) {
      short8 bfr = *(const short8*)(Wc + (nt * 4 + gp) * 128 + cr * 8);
      acc[0][nt] = __builtin_amdgcn_mfma_f32_16x16x32_bf16(af0, bfr, acc[0][nt], 0, 0, 0);
      acc[1][nt] = __builtin_amdgcn_mfma_f32_16x16x32_bf16(af1, bfr, acc[1][nt], 0, 0, 0);
    }
  }

#pragma unroll
  for (int mt = 0; mt < 2; ++mt)
#pragma unroll
    for (int nt = 0; nt < 8; ++nt)
#pragma unroll
      for (int rr = 0; rr < 4; ++rr)
        sH[(wrow + mt * 16 + gp * 4 + rr) * 136 + nt * 16 + cr] =
            (short)f2bf(fmaxf(acc[mt][nt][rr], 0.f));

  f32x4 acc2[2][8];
#pragma unroll
  for (int mt = 0; mt < 2; ++mt)
#pragma unroll
    for (int nt = 0; nt < 8; ++nt)
      acc2[mt][nt] = (f32x4){bia2[nt], bia2[nt], bia2[nt], bia2[nt]};
#pragma unroll
  for (int c2 = 0; c2 < 4; ++c2) {
    short8 af0 = *(const short8*)&sH[(wrow + cr) * 136 + c2 * 32 + gp * 8];
    short8 af1 = *(const short8*)&sH[(wrow + 16 + cr) * 136 + c2 * 32 + gp * 8];
    const short* Wc = U2p + c2 * 4096;
#pragma unroll
    for (int nt = 0; nt < 8; ++nt) {
      short8 bfr = *(const short8*)(Wc + (nt * 4 + gp) * 128 + cr * 8);
      acc2[0][nt] = __builtin_amdgcn_mfma_f32_16x16x32_bf16(af0, bfr, acc2[0][nt], 0, 0, 0);
      acc2[1][nt] = __builtin_amdgcn_mfma_f32_16x16x32_bf16(af1, bfr, acc2[1][nt], 0, 0, 0);
    }
  }

#pragma unroll
  for (int mt = 0; mt < 2; ++mt)
#pragma unroll
    for (int rr = 0; rr < 4; ++rr) {
      int n = n0 + wrow + mt * 16 + gp * 4 + rr;
      if (n < NN) {
#pragma unroll
        for (int nt = 0; nt < 8; ++nt) {
          int col = nt * 16 + cr;
          float r = bf2f((uint16_t)nfb[(size_t)n * ND + col]);
          out[(size_t)n * ND + col] = acc2[mt][nt][rr] + r;
        }
      }
    }
}

// ---------- fused online softmax reductions: (max,sum) pairs ----------
__device__ __forceinline__ void ms_combine(float& m, float& s, float m2, float s2) {
  float M = fmaxf(m, m2);
  s = s * expf(m - M) + s2 * expf(m2 - M);
  m = M;
}
__device__ __forceinline__ void ms_block_reduce(float& m, float& s) {
#pragma unroll
  for (int o = 1; o < 64; o <<= 1) {
    float m2 = __shfl_xor(m, o, 64), s2 = __shfl_xor(s, o, 64);
    ms_combine(m, s, m2, s2);
  }
  __shared__ float sm[4], ss[4];
  if ((threadIdx.x & 63) == 0) { sm[threadIdx.x >> 6] = m; ss[threadIdx.x >> 6] = s; }
  __syncthreads();
  m = sm[0]; s = ss[0];
  ms_combine(m, s, sm[1], ss[1]);
  ms_combine(m, s, sm[2], ss[2]);
  ms_combine(m, s, sm[3], ss[3]);
}
__global__ __launch_bounds__(256) void k_red_p(const float* __restrict__ logits,
                                               float* __restrict__ pmax,
                                               float* __restrict__ psum) {
  float m = -3.402823466e38f, s = 0.f;
  for (int i = blockIdx.x * 256 + threadIdx.x; i < NE; i += 1024 * 256) {
    float l = logits[i];
    if (l <= m) s += expf(l - m);
    else { s = s * expf(m - l) + 1.f; m = l; }
  }
  ms_block_reduce(m, s);
  if (threadIdx.x == 0) { pmax[blockIdx.x] = m; psum[blockIdx.x] = s; }
}
__global__ __launch_bounds__(256) void k_red_f(const float* __restrict__ pmax,
                                               const float* __restrict__ psum,
                                               float* __restrict__ red) {
  float m = pmax[threadIdx.x], s = psum[threadIdx.x];
  ms_combine(m, s, pmax[threadIdx.x + 256], psum[threadIdx.x + 256]);
  ms_combine(m, s, pmax[threadIdx.x + 512], psum[threadIdx.x + 512]);
  ms_combine(m, s, pmax[threadIdx.x + 768], psum[threadIdx.x + 768]);
  ms_block_reduce(m, s);
  if (threadIdx.x == 0) { red[0] = m; red[1] = 1.0f / s; }
}

// ---------- CSR build ----------
__global__ __launch_bounds__(256) void k_hist(const int* __restrict__ ei,
                                              int* __restrict__ cnt) {
  int e = blockIdx.x * 256 + threadIdx.x;
  if (e < NE) atomicAdd(&cnt[ei[NE + e]], 1);
}
__global__ __launch_bounds__(256) void k_scan_bsum(const int* __restrict__ cnt,
                                                   int* __restrict__ bsum) {
  int i = blockIdx.x * 256 + threadIdx.x;
  int v = (i < NN) ? cnt[i] : 0;
#pragma unroll
  for (int s = 1; s < 64; s <<= 1) v += __shfl_xor(v, s, 64);
  __shared__ int sv[4];
  if ((threadIdx.x & 63) == 0) sv[threadIdx.x >> 6] = v;
  __syncthreads();
  if (threadIdx.x == 0) bsum[blockIdx.x] = sv[0] + sv[1] + sv[2] + sv[3];
}
__global__ __launch_bounds__(512) void k_scan_boff(const int* __restrict__ bsum,
                                                   int* __restrict__ boff,
                                                   int* __restrict__ rowptr) {
  __shared__ int s[512];
  int t = threadIdx.x;
  int v = (t < SCANB) ? bsum[t] : 0;
  s[t] = v;
  __syncthreads();
  for (int off = 1; off < 512; off <<= 1) {
    int u = (t >= off) ? s[t - off] : 0;
    __syncthreads();
    s[t] += u;
    __syncthreads();
  }
  if (t < SCANB) boff[t] = s[t] - v;  // exclusive
  if (t == 0) rowptr[NN] = NE;
}
__global__ __launch_bounds__(256) void k_scan_final(int* __restrict__ cnt,
                                                    const int* __restrict__ boff,
                                                    int* __restrict__ rowptr) {
  __shared__ int s[256];
  int b = blockIdx.x, t = threadIdx.x, i = b * 256 + t;
  int v = (i < NN) ? cnt[i] : 0;
  s[t] = v;
  __syncthreads();
  for (int off = 1; off < 256; off <<= 1) {
    int u = (t >= off) ? s[t - off] : 0;
    __syncthreads();
    s[t] += u;
    __syncthreads();
  }
  int excl = s[t] - v + boff[b];
  if (i < NN) { rowptr[i] = excl; cnt[i] = excl; }  // cnt becomes the fill cursor
}
// fill: perm[e] = CSR slot of edge e
__global__ __launch_bounds__(256) void k_fill(const int* __restrict__ ei,
                                              int* __restrict__ cursor,
                                              int* __restrict__ perm) {
  int e = blockIdx.x * 256 + threadIdx.x;
  if (e >= NE) return;
  int c = ei[NE + e];
  int pos = atomicAdd(&cursor[c], 1);
  perm[e] = pos;
}

// ---------- CSR aggregate: streaming, writes bf16 agg ----------
__global__ __launch_bounds__(256) void k_agg(
    const uint8_t* __restrict__ msg8, const float* __restrict__ logits,
    const int* __restrict__ rowptr, const float* __restrict__ red,
    short* __restrict__ aggb) {
  int n = blockIdx.x * 4 + (threadIdx.x >> 6);
  int lane = threadIdx.x & 63;
  if (n >= NN) return;
  float gm = red[0], inv = red[1];
  int i0 = rowptr[n], i1 = rowptr[n + 1];
  float a0 = 0.f, a1 = 0.f;
  for (int i = i0; i < i1; ++i) {
    float wt = expf(logits[i] - gm) * inv;
    uint32_t pk = *(const uint16_t*)(msg8 + (size_t)i * HID + lane * 2);
    float2 d = fp8_dec2(pk);
    a0 += wt * d.x;
    a1 += wt * d.y;
  }
  uint32_t packed = f2bf(a0) | (f2bf(a1) << 16);
  *(uint32_t*)(aggb + (size_t)n * ND + lane * 2) = packed;
}

extern "C" void kernel_launch(void* const* d_in, const int* in_sizes, int n_in,
                              void* d_out, int out_size, void* d_ws, size_t ws_size,
                              hipStream_t stream) {
  const float* nf  = (const float*)d_in[0];
  const float* ef  = (const float*)d_in[1];
  const float* mW1 = (const float*)d_in[2];
  const float* mb1 = (const float*)d_in[3];
  const float* mW2 = (const float*)d_in[4];
  const float* mb2 = (const float*)d_in[5];
  const float* aW  = (const float*)d_in[6];
  // d_in[7] = a_b — unused (softmax is shift-invariant)
  const float* uW1 = (const float*)d_in[8];
  const float* ub1 = (const float*)d_in[9];
  const float* uW2 = (const float*)d_in[10];
  const float* ub2 = (const float*)d_in[11];
  const int*   ei  = (const int*)d_in[12];
  float* out = (float*)d_out;

  // ws layout (bytes):
  //   0          msg fp8 [NE*128] (CSR order)   76,800,000
  //   76800000   logits f32 [NE]  (CSR order)    2,400,000
  //   79200000   pmax[1024] psum[1024] red           8,256
  //   79208256   W1p8|W2p8 fp8, U1p|U2p bf16       151,552
  //   79413056   rowptr[NN+1] cnt[NN] perm[NE] bsum boff  3,204,100
  //   82620000   nfb bf16 [NN*128]              25,600,000
  //   108220000  nfb8 fp8 [NN*128]              12,800,000
  //   121020000  aggb bf16 [NN*128]             25,600,000  -> total ~146.6MB
  char* ws = (char*)d_ws;
  uint8_t* msg8 = (uint8_t*)ws;
  float* logits = (float*)(ws + 76800000);
  float* pmax = (float*)(ws + 79200000);
  float* psum = pmax + 1024;
  float* red  = psum + 1024;
  uint8_t* W1p8 = (uint8_t*)(ws + 79208256);
  uint8_t* W2p8 = W1p8 + 36864;
  short* U1p = (short*)(W2p8 + 16384);
  short* U2p = U1p + 32768;
  int* rowptr = (int*)(ws + 79413056);
  int* cnt    = rowptr + (NN + 1);
  int* perm   = cnt + NN;
  int* bsum   = perm + NE;
  int* boff   = bsum + 512;
  short* nfb  = (short*)(ws + 82620000);
  uint8_t* nfb8 = (uint8_t*)(ws + 108220000);
  short* aggb = (short*)(ws + 121020000);

  k_prep_all<<<400, 256, 0, stream>>>(uW1, uW2, mW1, mW2, U1p, U2p, W1p8, W2p8);
  k_prep_nf<<<2048, 256, 0, stream>>>(nf, nfb, nfb8, cnt);
  k_hist<<<(NE + 255) / 256, 256, 0, stream>>>(ei, cnt);
  k_scan_bsum<<<SCANB, 256, 0, stream>>>(cnt, bsum);
  k_scan_boff<<<1, 512, 0, stream>>>(bsum, boff, rowptr);
  k_scan_final<<<SCANB, 256, 0, stream>>>(cnt, boff, rowptr);
  k_fill<<<(NE + 255) / 256, 256, 0, stream>>>(ei, cnt, perm);
  k_edge_mfma<<<NEB, 256, 0, stream>>>(nfb8, ef, W1p8, mb1, W2p8, mb2, aW, ei, perm,
                                       msg8, logits);
  k_red_p<<<1024, 256, 0, stream>>>(logits, pmax, psum);
  k_red_f<<<1, 256, 0, stream>>>(pmax, psum, red);
  k_agg<<<(NN + 3) / 4, 256, 0, stream>>>(msg8, logits, rowptr, red, aggb);
  k_node_mfma<<<(NN + 127) / 128, 256, 0, stream>>>(nfb, aggb, U1p, ub1, U2p, ub2, out);
}